// Round 3
// baseline (221.012 us; speedup 1.0000x reference)
//
#include <hip/hip_runtime.h>
#include <hip/hip_bf16.h>
#include <math.h>

// Problem constants
#define HIDDEN 1024
#define HEADS  16
#define HDIM   64
#define BATCH  2
#define SEQ    2048
#define ROWS   (BATCH*SEQ)   // 4096
#define BH     (BATCH*HEADS) // 32

typedef __attribute__((ext_vector_type(8))) short  short8;
typedef __attribute__((ext_vector_type(8))) __bf16 bf16x8;
typedef __attribute__((ext_vector_type(4))) float  f32x4;
typedef __attribute__((ext_vector_type(4))) unsigned int uint4v;

static __device__ __forceinline__ unsigned short f2bf(float f) {
    unsigned int u = __builtin_bit_cast(unsigned int, f);
    u += 0x7FFFu + ((u >> 16) & 1u);   // round-to-nearest-even
    return (unsigned short)(u >> 16);
}
static __device__ __forceinline__ float bf2f(unsigned short h) {
    unsigned int u = ((unsigned int)h) << 16;
    return __builtin_bit_cast(float, u);
}
static __device__ __forceinline__ f32x4 mfma16(short8 a, short8 b, f32x4 c) {
    return __builtin_amdgcn_mfma_f32_16x16x32_bf16(
        __builtin_bit_cast(bf16x8, a), __builtin_bit_cast(bf16x8, b), c, 0, 0, 0);
}
// async global->LDS, 16B per lane; lds dest = wave-uniform base + lane*16
static __device__ __forceinline__ void gl_lds16(const unsigned short* g, unsigned short* l) {
    __builtin_amdgcn_global_load_lds(
        (const __attribute__((address_space(1))) unsigned int*)g,
        (__attribute__((address_space(3))) unsigned int*)l, 16, 0, 0);
}

// ---------------------------------------------------------------- prep: x->bf16 + W->bf16^T + consts
// grid 5120: blocks [0,4096) convert x (+ mod/pos tables in first 8); [4096,5120) transpose W.
__global__ __launch_bounds__(256) void prep_kernel(
    const float* __restrict__ x, unsigned short* __restrict__ xb,
    const float* __restrict__ w0, const float* __restrict__ w1,
    const float* __restrict__ w2, const float* __restrict__ w3,
    unsigned short* __restrict__ wt,
    const float* __restrict__ qp, const float* __restrict__ qa,
    float* __restrict__ mod, float* __restrict__ mod2,
    float* __restrict__ posc, float* __restrict__ poss) {
    __shared__ unsigned short tile[64][72];
    const int bid = blockIdx.x;
    const int t = threadIdx.x;
    if (bid < 4096) {
        int i = (bid * 256 + t) * 4;
        float4 v = *(const float4*)(x + i);
        ushort4 o;
        o.x = f2bf(v.x); o.y = f2bf(v.y); o.z = f2bf(v.z); o.w = f2bf(v.w);
        *(ushort4*)(xb + i) = o;
        if (bid < 8) {
            int k = bid * 256 + t;
            if (k < HIDDEN) {
                float m = cosf(qp[k]) * qa[k];
                mod[k] = m;
                mod2[k] = m * m * 0.18033688011112042f;   // mod^2 * 0.125 * log2(e)
            }
            if (k < SEQ) {
                float ang = (float)k * (6.283185307179586f / (float)SEQ);
                posc[k] = cosf(ang);
                poss[k] = sinf(ang);
            }
        }
        return;
    }
    int rem = bid - 4096;
    int z = rem >> 8, r2 = rem & 255;
    int n0 = (r2 & 15) * 64, k0 = (r2 >> 4) * 64;
    const float* src = (z == 0) ? w0 : (z == 1) ? w1 : (z == 2) ? w2 : w3;
    unsigned short* dst = wt + (size_t)z * HIDDEN * HIDDEN;
    int cg = t & 15, r0 = t >> 4;
#pragma unroll
    for (int rr = 0; rr < 4; rr++) {
        int kl = r0 + rr * 16;
        float4 v = *(const float4*)(src + (size_t)(k0 + kl) * HIDDEN + n0 + cg * 4);
        tile[cg*4+0][kl] = f2bf(v.x);
        tile[cg*4+1][kl] = f2bf(v.y);
        tile[cg*4+2][kl] = f2bf(v.z);
        tile[cg*4+3][kl] = f2bf(v.w);
    }
    __syncthreads();
#pragma unroll
    for (int rr = 0; rr < 4; rr++) {
        int nl = r0 + rr * 16;
        ushort4 o;
        o.x = tile[nl][cg*4+0]; o.y = tile[nl][cg*4+1];
        o.z = tile[nl][cg*4+2]; o.w = tile[nl][cg*4+3];
        *(ushort4*)(dst + (size_t)(n0 + nl) * HIDDEN + k0 + cg * 4) = o;
    }
}

// ---------------------------------------------------------------- GEMM QKV: 128x128 tile, BK=64
// grid (32,8,3) = 768 blocks = 3/CU (LDS 32 KB). mode 0/1: plain bf16 C; mode 2: C*mod.
__global__ __launch_bounds__(256) void gemm_kernel(
    const unsigned short* __restrict__ A, const unsigned short* __restrict__ WtBase,
    unsigned short* __restrict__ CBase, const float* __restrict__ mod) {
    __shared__ unsigned short Alds[128 * 64];   // 16 KB
    __shared__ unsigned short Blds[128 * 64];   // 16 KB
    const int mode = blockIdx.z;
    const unsigned short* Bt = WtBase + (size_t)mode * HIDDEN * HIDDEN;
    unsigned short* Cout = CBase + (size_t)mode * ROWS * HIDDEN;
    const int m0 = blockIdx.x * 128, n0 = blockIdx.y * 128;
    const int tid = threadIdx.x;
    const int wave = tid >> 6, lane = tid & 63, quad = lane >> 4, l15 = lane & 15;
    const int wr = wave >> 1, wc = wave & 1;
    const int srow = lane >> 3;
    const int schunk = (lane & 7) ^ (srow & 7);

    f32x4 acc[4][4];
    const f32x4 z4 = {0.f, 0.f, 0.f, 0.f};
#pragma unroll
    for (int i = 0; i < 4; i++)
#pragma unroll
        for (int j = 0; j < 4; j++) acc[i][j] = z4;

    for (int k0 = 0; k0 < HIDDEN; k0 += 64) {
#pragma unroll
        for (int p = 0; p < 4; p++) {
            int rbase = p * 32 + wave * 8;
            gl_lds16(A + (size_t)(m0 + rbase + srow) * HIDDEN + k0 + schunk * 8,
                     &Alds[rbase * 64]);
        }
#pragma unroll
        for (int p = 0; p < 4; p++) {
            int rbase = p * 32 + wave * 8;
            gl_lds16(Bt + (size_t)(n0 + rbase + srow) * HIDDEN + k0 + schunk * 8,
                     &Blds[rbase * 64]);
        }
        __syncthreads();
        short8 aF[4][2], bF[4][2];
#pragma unroll
        for (int h = 0; h < 2; h++) {
#pragma unroll
            for (int i = 0; i < 4; i++) {
                int row = wr * 64 + i * 16 + l15;
                aF[i][h] = *(const short8*)(&Alds[row * 64 + ((h * 4 + quad) ^ (l15 & 7)) * 8]);
            }
#pragma unroll
            for (int j = 0; j < 4; j++) {
                int row = wc * 64 + j * 16 + l15;
                bF[j][h] = *(const short8*)(&Blds[row * 64 + ((h * 4 + quad) ^ (l15 & 7)) * 8]);
            }
        }
#pragma unroll
        for (int h = 0; h < 2; h++)
#pragma unroll
            for (int i = 0; i < 4; i++)
#pragma unroll
                for (int j = 0; j < 4; j++)
                    acc[i][j] = mfma16(aF[i][h], bF[j][h], acc[i][j]);
        __syncthreads();
    }

#pragma unroll
    for (int i = 0; i < 4; i++) {
        int mbase = m0 + wr * 64 + i * 16 + quad * 4;
#pragma unroll
        for (int j = 0; j < 4; j++) {
            int n = n0 + wc * 64 + j * 16 + l15;
            float vm = (mode == 2) ? mod[n] : 1.0f;
#pragma unroll
            for (int r = 0; r < 4; r++) {
                int mm = mbase + r;
                Cout[(size_t)mm * HIDDEN + n] = f2bf(acc[i][j][r] * vm);
            }
        }
    }
}

// ---------------------------------------------------------------- GEMM O: 128x64 tile, BK=64
// grid (32,16) = 512 blocks = 2/CU. fp32 out.
__global__ __launch_bounds__(256) void gemm_o_kernel(
    const unsigned short* __restrict__ A, const unsigned short* __restrict__ Bt,
    float* __restrict__ Out) {
    __shared__ unsigned short Alds[128 * 64];   // 16 KB
    __shared__ unsigned short Blds[64 * 64];    // 8 KB
    const int m0 = blockIdx.x * 128, n0 = blockIdx.y * 64;
    const int tid = threadIdx.x;
    const int wave = tid >> 6, lane = tid & 63, quad = lane >> 4, l15 = lane & 15;
    const int wr = wave >> 1, wc = wave & 1;
    const int srow = lane >> 3;
    const int schunk = (lane & 7) ^ (srow & 7);

    f32x4 acc[4][2];
    const f32x4 z4 = {0.f, 0.f, 0.f, 0.f};
#pragma unroll
    for (int i = 0; i < 4; i++)
#pragma unroll
        for (int j = 0; j < 2; j++) acc[i][j] = z4;

    for (int k0 = 0; k0 < HIDDEN; k0 += 64) {
#pragma unroll
        for (int p = 0; p < 4; p++) {
            int rbase = p * 32 + wave * 8;
            gl_lds16(A + (size_t)(m0 + rbase + srow) * HIDDEN + k0 + schunk * 8,
                     &Alds[rbase * 64]);
        }
#pragma unroll
        for (int p = 0; p < 2; p++) {
            int rbase = p * 32 + wave * 8;
            gl_lds16(Bt + (size_t)(n0 + rbase + srow) * HIDDEN + k0 + schunk * 8,
                     &Blds[rbase * 64]);
        }
        __syncthreads();
        short8 aF[4][2], bF[2][2];
#pragma unroll
        for (int h = 0; h < 2; h++) {
#pragma unroll
            for (int i = 0; i < 4; i++) {
                int row = wr * 64 + i * 16 + l15;
                aF[i][h] = *(const short8*)(&Alds[row * 64 + ((h * 4 + quad) ^ (l15 & 7)) * 8]);
            }
#pragma unroll
            for (int j = 0; j < 2; j++) {
                int row = wc * 32 + j * 16 + l15;
                bF[j][h] = *(const short8*)(&Blds[row * 64 + ((h * 4 + quad) ^ (l15 & 7)) * 8]);
            }
        }
#pragma unroll
        for (int h = 0; h < 2; h++)
#pragma unroll
            for (int i = 0; i < 4; i++)
#pragma unroll
                for (int j = 0; j < 2; j++)
                    acc[i][j] = mfma16(aF[i][h], bF[j][h], acc[i][j]);
        __syncthreads();
    }

#pragma unroll
    for (int i = 0; i < 4; i++) {
        int mbase = m0 + wr * 64 + i * 16 + quad * 4;
#pragma unroll
        for (int j = 0; j < 2; j++) {
            int n = n0 + wc * 32 + j * 16 + l15;
#pragma unroll
            for (int r = 0; r < 4; r++)
                Out[(size_t)(mbase + r) * HIDDEN + n] = acc[i][j][r];
        }
    }
}

// ---------------------------------------------------------------- V shift + transpose (mod pre-folded in gemm)
// Vpt[bh][d][s] = (Vm[s][d] + Vm[(s+1)%S][d])/sqrt2. grid = (bh=32, stile=32).
__global__ __launch_bounds__(256) void vshift_kernel(const unsigned short* __restrict__ Vm,
                                                     unsigned short* __restrict__ Vpt) {
    __shared__ unsigned short lds[65][72];
    int bh = blockIdx.x, b = bh >> 4, h = bh & 15;
    int s0 = blockIdx.y * 64;
    int t = threadIdx.x;
    int cg = t & 15, r0 = t >> 4;
#pragma unroll
    for (int rr = 0; rr < 4; rr++) {
        int row = r0 + rr * 16;
        ushort4 v = *(const ushort4*)(Vm + ((size_t)(b * SEQ + s0 + row)) * HIDDEN + h * 64 + cg * 4);
        *(ushort4*)(&lds[row][cg * 4]) = v;
    }
    if (t < 16) {
        int srow = (s0 + 64) & (SEQ - 1);
        ushort4 v = *(const ushort4*)(Vm + ((size_t)(b * SEQ + srow)) * HIDDEN + h * 64 + t * 4);
        *(ushort4*)(&lds[64][t * 4]) = v;
    }
    __syncthreads();
    int d = t & 63, sb = (t >> 6) * 16;
    unsigned short outv[16];
#pragma unroll
    for (int k = 0; k < 16; k++) {
        float a = bf2f(lds[sb + k][d]), bb = bf2f(lds[sb + k + 1][d]);
        outv[k] = f2bf((a + bb) * 0.7071067811865476f);
    }
    unsigned short* dst = Vpt + ((size_t)bh * 64 + d) * SEQ + s0 + sb;
#pragma unroll
    for (int k = 0; k < 16; k += 4) {
        ushort4 o; o.x = outv[k]; o.y = outv[k+1]; o.z = outv[k+2]; o.w = outv[k+3];
        *(ushort4*)(dst + k) = o;
    }
}

// ---------------------------------------------------------------- flash attention (KT=128)
// R16 (proven): swapped QK^T (mfma(K,Q)) + in-register P via v_cvt_pk_bf16_f32 + permlane32/16_swap.
#define KT 128
__global__ __launch_bounds__(256) void attn_kernel(const unsigned short* __restrict__ Cq,
                                                   const unsigned short* __restrict__ Ck,
                                                   const unsigned short* __restrict__ Vpt,
                                                   unsigned short* __restrict__ Ob,
                                                   const float* __restrict__ mod2,
                                                   const float* __restrict__ posc,
                                                   const float* __restrict__ poss) {
    __shared__ unsigned short Klds[2][KT * 64];      // 2 x 16 KB, XOR-swizzled
    __shared__ unsigned short Vtlds[2][64 * 128];    // 2 x 16 KB, XOR-swizzled
    const int bh = blockIdx.x;
    const int b = bh >> 4, h = bh & 15;
    const int tid = threadIdx.x, wave = tid >> 6, lane = tid & 63;
    const int quad = lane >> 4, l15 = lane & 15;
    const int q0 = blockIdx.y * 128 + wave * 32;

    // Q fragments (mod^2*scale*log2e folded); used as MFMA *B* operand.
    short8 qf[2][2];
#pragma unroll
    for (int g = 0; g < 2; g++) {
        int ss = q0 + g * 16 + l15;
        const unsigned short* crow = Cq + ((size_t)(b * SEQ + ss)) * HIDDEN + h * 64;
#pragma unroll
        for (int kk = 0; kk < 2; kk++) {
            int bd = kk * 32 + quad * 8;
            short8 u = *(const short8*)(crow + bd);
            short8 q;
#pragma unroll
            for (int e = 0; e < 8; e++)
                q[e] = (short)f2bf(bf2f((unsigned short)u[e]) * mod2[h * 64 + bd + e]);
            qf[g][kk] = q;
        }
    }
    // interference weights for the q side: q index = q0 + g*16 + l15 (lane-scalar per g)
    float ci_[2], si_[2];
#pragma unroll
    for (int g = 0; g < 2; g++) {
        ci_[g] = posc[q0 + g * 16 + l15];
        si_[g] = poss[q0 + g * 16 + l15];
    }

    short8 ones;
#pragma unroll
    for (int e = 0; e < 8; e++) ones[e] = (short)0x3F80;

    const f32x4 z4 = {0.f, 0.f, 0.f, 0.f};
    f32x4 acc[2][4], accden[2];
#pragma unroll
    for (int g = 0; g < 2; g++) {
#pragma unroll
        for (int dt = 0; dt < 4; dt++) acc[g][dt] = z4;
        accden[g] = z4;
    }

    const unsigned short* Kbh = Ck  + ((size_t)b * SEQ) * HIDDEN + h * 64;   // row stride HIDDEN
    const unsigned short* Vbh = Vpt + (size_t)bh * 64 * SEQ;                 // row stride SEQ

    auto stage = [&](int j, int buf) {
#pragma unroll
        for (int p = 0; p < 4; p++) {               // K: 128 rows, 8 rows/instr/wave
            int rb = p * 32 + wave * 8;
            int r  = rb + (lane >> 3);
            int c  = (lane & 7) ^ (r & 7);
            gl_lds16(Kbh + (size_t)(j + r) * HIDDEN + c * 8, &Klds[buf][rb * 64]);
        }
#pragma unroll
        for (int p = 0; p < 4; p++) {               // V^T: 64 rows x 128 keys, 4 rows/instr/wave
            int rb = p * 16 + wave * 4;
            int r  = rb + (lane >> 4);
            int c  = (lane & 15) ^ (r & 15);
            gl_lds16(Vbh + (size_t)r * SEQ + j + c * 8, &Vtlds[buf][rb * 128]);
        }
    };

    stage(0, 0);
    const int NIT = SEQ / KT;   // 16
    for (int it = 0; it < NIT; it++) {
        __syncthreads();                 // drains stage(it); prev-buf reads done
        if (it + 1 < NIT) stage((it + 1) * KT, (it + 1) & 1);   // overlap w/ compute
        const int buf = it & 1;

        // 4 chunks of 32 keys: QK (swapped operands) -> in-reg P -> PV
#pragma unroll
        for (int chunk = 0; chunk < 4; chunk++) {
            // cos/sin for this chunk's 32 keys: key = it*KT + chunk*32 + quad*4 + r (+16 for t2i=1)
            const int jb = it * KT + chunk * 32 + quad * 4;
            f32x4 cjA[2], sjA[2];
            cjA[0] = *(const f32x4*)(posc + jb);
            sjA[0] = *(const f32x4*)(poss + jb);
            cjA[1] = *(const f32x4*)(posc + jb + 16);
            sjA[1] = *(const f32x4*)(poss + jb + 16);

            f32x4 sc[2][2];   // [g][t2i]; C row = key quad*4+r, col = q l15
            sc[0][0] = z4; sc[0][1] = z4; sc[1][0] = z4; sc[1][1] = z4;
            __builtin_amdgcn_s_setprio(1);
#pragma unroll
            for (int t2i = 0; t2i < 2; t2i++) {
                int tt = chunk * 2 + t2i;
#pragma unroll
                for (int kk = 0; kk < 2; kk++) {
                    int ch = (kk * 4 + quad) ^ (l15 & 7);
                    short8 kf = *(const short8*)(&Klds[buf][(tt * 16 + l15) * 64 + ch * 8]);
                    sc[0][t2i] = mfma16(kf, qf[0][kk], sc[0][t2i]);
                    sc[1][t2i] = mfma16(kf, qf[1][kk], sc[1][t2i]);
                }
            }
            __builtin_amdgcn_s_setprio(0);

            // softmax + pack + quad-butterfly -> PV A-fragment, fully in registers
            short8 pa[2];
#pragma unroll
            for (int g = 0; g < 2; g++) {
                unsigned int w_[4];   // w_[t2i*2+hp]: keys tt*16 + quad*4 + 2hp..2hp+1, q = l15
#pragma unroll
                for (int t2i = 0; t2i < 2; t2i++) {
#pragma unroll
                    for (int hp = 0; hp < 2; hp++) {
                        float wl = ci_[g] * cjA[t2i][2 * hp]     + si_[g] * sjA[t2i][2 * hp];
                        float wh = ci_[g] * cjA[t2i][2 * hp + 1] + si_[g] * sjA[t2i][2 * hp + 1];
                        float pl = __builtin_amdgcn_exp2f(sc[g][t2i][2 * hp]     * wl);
                        float ph = __builtin_amdgcn_exp2f(sc[g][t2i][2 * hp + 1] * wh);
                        unsigned int w;
                        asm("v_cvt_pk_bf16_f32 %0, %1, %2" : "=v"(w) : "v"(pl), "v"(ph));
                        w_[t2i * 2 + hp] = w;
                    }
                }
                // 4x4 quad-group transpose: (w0,w2)->P32->P16 gives {A0,A2}; (w1,w3) gives {A1,A3}
                auto t02 = __builtin_amdgcn_permlane32_swap(w_[0], w_[2], false, false);
                auto a02 = __builtin_amdgcn_permlane16_swap(t02[0], t02[1], false, false);
                auto t13 = __builtin_amdgcn_permlane32_swap(w_[1], w_[3], false, false);
                auto a13 = __builtin_amdgcn_permlane16_swap(t13[0], t13[1], false, false);
                uint4v pword;
                pword[0] = a02[0]; pword[1] = a13[0]; pword[2] = a02[1]; pword[3] = a13[1];
                pa[g] = __builtin_bit_cast(short8, pword);   // A[row=q l15][k=quad*8+e]
                accden[g] = mfma16(pa[g], ones, accden[g]);
            }

            __builtin_amdgcn_s_setprio(1);
#pragma unroll
            for (int dt = 0; dt < 4; dt++) {
                int ch = (chunk * 4 + quad) ^ l15;
                short8 vb = *(const short8*)(&Vtlds[buf][(dt * 16 + l15) * 128 + ch * 8]);
                acc[0][dt] = mfma16(pa[0], vb, acc[0][dt]);
                acc[1][dt] = mfma16(pa[1], vb, acc[1][dt]);
            }
            __builtin_amdgcn_s_setprio(0);
        }
    }

#pragma unroll
    for (int g = 0; g < 2; g++) {
        float rinv[4];
#pragma unroll
        for (int r = 0; r < 4; r++) rinv[r] = 1.0f / accden[g][r];
#pragma unroll
        for (int dt = 0; dt < 4; dt++) {
#pragma unroll
            for (int r = 0; r < 4; r++) {
                int q = q0 + g * 16 + quad * 4 + r;
                int d = dt * 16 + l15;
                Ob[((size_t)(b * SEQ + q)) * HIDDEN + h * 64 + d] = f2bf(acc[g][dt][r] * rinv[r]);
            }
        }
    }
}

// ---------------------------------------------------------------- launch
extern "C" void kernel_launch(void* const* d_in, const int* in_sizes, int n_in,
                              void* d_out, int out_size, void* d_ws, size_t ws_size,
                              hipStream_t stream) {
    const float* x  = (const float*)d_in[0];
    const float* Wq = (const float*)d_in[1];
    const float* Wk = (const float*)d_in[2];
    const float* Wv = (const float*)d_in[3];
    const float* Wo = (const float*)d_in[4];
    const float* qp = (const float*)d_in[5];
    const float* qa = (const float*)d_in[6];
    char* ws = (char*)d_ws;

    unsigned short* Xb  = (unsigned short*)(ws);                      // 8 MB (reused as Ob)
    unsigned short* Wt  = (unsigned short*)(ws + (size_t)( 8 << 20)); // 8 MB (4 x 2MB)
    unsigned short* Cq  = (unsigned short*)(ws + (size_t)(16 << 20)); // 8 MB
    unsigned short* Ck  = (unsigned short*)(ws + (size_t)(24 << 20)); // 8 MB
    unsigned short* Cv  = (unsigned short*)(ws + (size_t)(32 << 20)); // 8 MB (holds V*mod)
    unsigned short* Vpt = (unsigned short*)(ws + (size_t)(40 << 20)); // 8 MB
    float* mod  = (float*)(ws + (size_t)(48 << 20));
    float* mod2 = mod + 1024;
    float* posc = mod2 + 1024;
    float* poss = posc + 2048;
    float* out  = (float*)d_out;

    prep_kernel<<<5120, 256, 0, stream>>>(x, Xb, Wq, Wk, Wv, Wo, Wt,
                                          qp, qa, mod, mod2, posc, poss);
    gemm_kernel<<<dim3(32, 8, 3), 256, 0, stream>>>(Xb, Wt, Cq, mod);  // -> Cq,Ck,Cv(modded)
    vshift_kernel<<<dim3(32, 32), 256, 0, stream>>>(Cv, Vpt);
    attn_kernel<<<dim3(32, 16), 256, 0, stream>>>(Cq, Ck, Vpt, Xb /*Ob*/, mod2, posc, poss);
    gemm_o_kernel<<<dim3(32, 16), 256, 0, stream>>>(Xb, Wt + (size_t)3 * HIDDEN * HIDDEN, out);
}

// Round 4
// 207.102 us; speedup vs baseline: 1.0672x; 1.0672x over previous
//
#include <hip/hip_runtime.h>
#include <hip/hip_bf16.h>
#include <math.h>

// Problem constants
#define HIDDEN 1024
#define HEADS  16
#define HDIM   64
#define BATCH  2
#define SEQ    2048
#define ROWS   (BATCH*SEQ)   // 4096
#define BH     (BATCH*HEADS) // 32

typedef __attribute__((ext_vector_type(8))) short  short8;
typedef __attribute__((ext_vector_type(8))) __bf16 bf16x8;
typedef __attribute__((ext_vector_type(4))) float  f32x4;
typedef __attribute__((ext_vector_type(4))) unsigned int uint4v;

static __device__ __forceinline__ unsigned short f2bf(float f) {
    unsigned int u = __builtin_bit_cast(unsigned int, f);
    u += 0x7FFFu + ((u >> 16) & 1u);   // round-to-nearest-even
    return (unsigned short)(u >> 16);
}
static __device__ __forceinline__ float bf2f(unsigned short h) {
    unsigned int u = ((unsigned int)h) << 16;
    return __builtin_bit_cast(float, u);
}
static __device__ __forceinline__ f32x4 mfma16(short8 a, short8 b, f32x4 c) {
    return __builtin_amdgcn_mfma_f32_16x16x32_bf16(
        __builtin_bit_cast(bf16x8, a), __builtin_bit_cast(bf16x8, b), c, 0, 0, 0);
}
// async global->LDS, 16B per lane; lds dest = wave-uniform base + lane*16
static __device__ __forceinline__ void gl_lds16(const unsigned short* g, unsigned short* l) {
    __builtin_amdgcn_global_load_lds(
        (const __attribute__((address_space(1))) unsigned int*)g,
        (__attribute__((address_space(3))) unsigned int*)l, 16, 0, 0);
}

// ---------------------------------------------------------------- prep: x->bf16 + W->bf16^T + consts
// grid 5120: blocks [0,4096) convert x (+ mod/pos tables in first 8); [4096,5120) transpose W.
__global__ __launch_bounds__(256) void prep_kernel(
    const float* __restrict__ x, unsigned short* __restrict__ xb,
    const float* __restrict__ w0, const float* __restrict__ w1,
    const float* __restrict__ w2, const float* __restrict__ w3,
    unsigned short* __restrict__ wt,
    const float* __restrict__ qp, const float* __restrict__ qa,
    float* __restrict__ mod, float* __restrict__ mod2,
    float* __restrict__ posc, float* __restrict__ poss) {
    __shared__ unsigned short tile[64][72];
    const int bid = blockIdx.x;
    const int t = threadIdx.x;
    if (bid < 4096) {
        int i = (bid * 256 + t) * 4;
        float4 v = *(const float4*)(x + i);
        ushort4 o;
        o.x = f2bf(v.x); o.y = f2bf(v.y); o.z = f2bf(v.z); o.w = f2bf(v.w);
        *(ushort4*)(xb + i) = o;
        if (bid < 8) {
            int k = bid * 256 + t;
            if (k < HIDDEN) {
                float m = cosf(qp[k]) * qa[k];
                mod[k] = m;
                mod2[k] = m * m * 0.18033688011112042f;   // mod^2 * 0.125 * log2(e)
            }
            if (k < SEQ) {
                float ang = (float)k * (6.283185307179586f / (float)SEQ);
                posc[k] = cosf(ang);
                poss[k] = sinf(ang);
            }
        }
        return;
    }
    int rem = bid - 4096;
    int z = rem >> 8, r2 = rem & 255;
    int n0 = (r2 & 15) * 64, k0 = (r2 >> 4) * 64;
    const float* src = (z == 0) ? w0 : (z == 1) ? w1 : (z == 2) ? w2 : w3;
    unsigned short* dst = wt + (size_t)z * HIDDEN * HIDDEN;
    int cg = t & 15, r0 = t >> 4;
#pragma unroll
    for (int rr = 0; rr < 4; rr++) {
        int kl = r0 + rr * 16;
        float4 v = *(const float4*)(src + (size_t)(k0 + kl) * HIDDEN + n0 + cg * 4);
        tile[cg*4+0][kl] = f2bf(v.x);
        tile[cg*4+1][kl] = f2bf(v.y);
        tile[cg*4+2][kl] = f2bf(v.z);
        tile[cg*4+3][kl] = f2bf(v.w);
    }
    __syncthreads();
#pragma unroll
    for (int rr = 0; rr < 4; rr++) {
        int nl = r0 + rr * 16;
        ushort4 o;
        o.x = tile[nl][cg*4+0]; o.y = tile[nl][cg*4+1];
        o.z = tile[nl][cg*4+2]; o.w = tile[nl][cg*4+3];
        *(ushort4*)(dst + (size_t)(n0 + nl) * HIDDEN + k0 + cg * 4) = o;
    }
}

// ---------------------------------------------------------------- GEMM QKV: 128x64 tile, BK=64
// grid (32,16,3) = 1536 blocks = 6/CU dispatched (LDS 24 KB). mode 0/1: plain bf16 C;
// mode 2: C*mod (V-mod folded). (R18's 128x128 tile measured neutral-to-worse; reverted.)
__global__ __launch_bounds__(256) void gemm_kernel(
    const unsigned short* __restrict__ A, const unsigned short* __restrict__ WtBase,
    unsigned short* __restrict__ CBase, const float* __restrict__ mod) {
    __shared__ unsigned short Alds[128 * 64];   // 16 KB
    __shared__ unsigned short Blds[64 * 64];    // 8 KB
    const int mode = blockIdx.z;
    const unsigned short* Bt = WtBase + (size_t)mode * HIDDEN * HIDDEN;
    unsigned short* Cout = CBase + (size_t)mode * ROWS * HIDDEN;
    const int m0 = blockIdx.x * 128, n0 = blockIdx.y * 64;
    const int tid = threadIdx.x;
    const int wave = tid >> 6, lane = tid & 63, quad = lane >> 4, l15 = lane & 15;
    const int wr = wave >> 1, wc = wave & 1;
    const int srow = lane >> 3;
    const int schunk = (lane & 7) ^ (srow & 7);

    f32x4 acc[4][2];
    const f32x4 z4 = {0.f, 0.f, 0.f, 0.f};
#pragma unroll
    for (int i = 0; i < 4; i++)
#pragma unroll
        for (int j = 0; j < 2; j++) acc[i][j] = z4;

    for (int k0 = 0; k0 < HIDDEN; k0 += 64) {
#pragma unroll
        for (int p = 0; p < 4; p++) {
            int rbase = p * 32 + wave * 8;
            gl_lds16(A + (size_t)(m0 + rbase + srow) * HIDDEN + k0 + schunk * 8,
                     &Alds[rbase * 64]);
        }
#pragma unroll
        for (int p = 0; p < 2; p++) {
            int rbase = p * 32 + wave * 8;
            gl_lds16(Bt + (size_t)(n0 + rbase + srow) * HIDDEN + k0 + schunk * 8,
                     &Blds[rbase * 64]);
        }
        __syncthreads();
        short8 aF[4][2], bF[2][2];
#pragma unroll
        for (int h = 0; h < 2; h++) {
#pragma unroll
            for (int i = 0; i < 4; i++) {
                int row = wr * 64 + i * 16 + l15;
                aF[i][h] = *(const short8*)(&Alds[row * 64 + ((h * 4 + quad) ^ (l15 & 7)) * 8]);
            }
#pragma unroll
            for (int j = 0; j < 2; j++) {
                int row = wc * 32 + j * 16 + l15;
                bF[j][h] = *(const short8*)(&Blds[row * 64 + ((h * 4 + quad) ^ (l15 & 7)) * 8]);
            }
        }
#pragma unroll
        for (int h = 0; h < 2; h++)
#pragma unroll
            for (int i = 0; i < 4; i++)
#pragma unroll
                for (int j = 0; j < 2; j++)
                    acc[i][j] = mfma16(aF[i][h], bF[j][h], acc[i][j]);
        __syncthreads();
    }

#pragma unroll
    for (int i = 0; i < 4; i++) {
        int mbase = m0 + wr * 64 + i * 16 + quad * 4;
#pragma unroll
        for (int j = 0; j < 2; j++) {
            int n = n0 + wc * 32 + j * 16 + l15;
            float vm = (mode == 2) ? mod[n] : 1.0f;
#pragma unroll
            for (int r = 0; r < 4; r++) {
                int mm = mbase + r;
                Cout[(size_t)mm * HIDDEN + n] = f2bf(acc[i][j][r] * vm);
            }
        }
    }
}

// ---------------------------------------------------------------- GEMM O: 128x64 tile, BK=64
// grid (32,16) = 512 blocks = 2/CU. fp32 out.
__global__ __launch_bounds__(256) void gemm_o_kernel(
    const unsigned short* __restrict__ A, const unsigned short* __restrict__ Bt,
    float* __restrict__ Out) {
    __shared__ unsigned short Alds[128 * 64];   // 16 KB
    __shared__ unsigned short Blds[64 * 64];    // 8 KB
    const int m0 = blockIdx.x * 128, n0 = blockIdx.y * 64;
    const int tid = threadIdx.x;
    const int wave = tid >> 6, lane = tid & 63, quad = lane >> 4, l15 = lane & 15;
    const int wr = wave >> 1, wc = wave & 1;
    const int srow = lane >> 3;
    const int schunk = (lane & 7) ^ (srow & 7);

    f32x4 acc[4][2];
    const f32x4 z4 = {0.f, 0.f, 0.f, 0.f};
#pragma unroll
    for (int i = 0; i < 4; i++)
#pragma unroll
        for (int j = 0; j < 2; j++) acc[i][j] = z4;

    for (int k0 = 0; k0 < HIDDEN; k0 += 64) {
#pragma unroll
        for (int p = 0; p < 4; p++) {
            int rbase = p * 32 + wave * 8;
            gl_lds16(A + (size_t)(m0 + rbase + srow) * HIDDEN + k0 + schunk * 8,
                     &Alds[rbase * 64]);
        }
#pragma unroll
        for (int p = 0; p < 2; p++) {
            int rbase = p * 32 + wave * 8;
            gl_lds16(Bt + (size_t)(n0 + rbase + srow) * HIDDEN + k0 + schunk * 8,
                     &Blds[rbase * 64]);
        }
        __syncthreads();
        short8 aF[4][2], bF[2][2];
#pragma unroll
        for (int h = 0; h < 2; h++) {
#pragma unroll
            for (int i = 0; i < 4; i++) {
                int row = wr * 64 + i * 16 + l15;
                aF[i][h] = *(const short8*)(&Alds[row * 64 + ((h * 4 + quad) ^ (l15 & 7)) * 8]);
            }
#pragma unroll
            for (int j = 0; j < 2; j++) {
                int row = wc * 32 + j * 16 + l15;
                bF[j][h] = *(const short8*)(&Blds[row * 64 + ((h * 4 + quad) ^ (l15 & 7)) * 8]);
            }
        }
#pragma unroll
        for (int h = 0; h < 2; h++)
#pragma unroll
            for (int i = 0; i < 4; i++)
#pragma unroll
                for (int j = 0; j < 2; j++)
                    acc[i][j] = mfma16(aF[i][h], bF[j][h], acc[i][j]);
        __syncthreads();
    }

#pragma unroll
    for (int i = 0; i < 4; i++) {
        int mbase = m0 + wr * 64 + i * 16 + quad * 4;
#pragma unroll
        for (int j = 0; j < 2; j++) {
            int n = n0 + wc * 32 + j * 16 + l15;
#pragma unroll
            for (int r = 0; r < 4; r++)
                Out[(size_t)(mbase + r) * HIDDEN + n] = acc[i][j][r];
        }
    }
}

// ---------------------------------------------------------------- V shift + transpose (mod pre-folded in gemm)
// Vpt[bh][d][s] = (Vm[s][d] + Vm[(s+1)%S][d])/sqrt2. grid = (bh=32, stile=32).
__global__ __launch_bounds__(256) void vshift_kernel(const unsigned short* __restrict__ Vm,
                                                     unsigned short* __restrict__ Vpt) {
    __shared__ unsigned short lds[65][72];
    int bh = blockIdx.x, b = bh >> 4, h = bh & 15;
    int s0 = blockIdx.y * 64;
    int t = threadIdx.x;
    int cg = t & 15, r0 = t >> 4;
#pragma unroll
    for (int rr = 0; rr < 4; rr++) {
        int row = r0 + rr * 16;
        ushort4 v = *(const ushort4*)(Vm + ((size_t)(b * SEQ + s0 + row)) * HIDDEN + h * 64 + cg * 4);
        *(ushort4*)(&lds[row][cg * 4]) = v;
    }
    if (t < 16) {
        int srow = (s0 + 64) & (SEQ - 1);
        ushort4 v = *(const ushort4*)(Vm + ((size_t)(b * SEQ + srow)) * HIDDEN + h * 64 + t * 4);
        *(ushort4*)(&lds[64][t * 4]) = v;
    }
    __syncthreads();
    int d = t & 63, sb = (t >> 6) * 16;
    unsigned short outv[16];
#pragma unroll
    for (int k = 0; k < 16; k++) {
        float a = bf2f(lds[sb + k][d]), bb = bf2f(lds[sb + k + 1][d]);
        outv[k] = f2bf((a + bb) * 0.7071067811865476f);
    }
    unsigned short* dst = Vpt + ((size_t)bh * 64 + d) * SEQ + s0 + sb;
#pragma unroll
    for (int k = 0; k < 16; k += 4) {
        ushort4 o; o.x = outv[k]; o.y = outv[k+1]; o.z = outv[k+2]; o.w = outv[k+3];
        *(ushort4*)(dst + k) = o;
    }
}

// ---------------------------------------------------------------- flash attention (KT=128)
// R19: R16 + in-wave chunk pipelining. QK(c+1) K-reads + MFMAs issue BEFORE softmax(c);
// V-reads for chunk c issue at chunk top. Softmax consumes scores computed one chunk
// earlier -> QK latency hidden under exp/permlane chain. Pure code motion vs R16.
#define KT 128
__global__ __launch_bounds__(256) void attn_kernel(const unsigned short* __restrict__ Cq,
                                                   const unsigned short* __restrict__ Ck,
                                                   const unsigned short* __restrict__ Vpt,
                                                   unsigned short* __restrict__ Ob,
                                                   const float* __restrict__ mod2,
                                                   const float* __restrict__ posc,
                                                   const float* __restrict__ poss) {
    __shared__ unsigned short Klds[2][KT * 64];      // 2 x 16 KB, XOR-swizzled
    __shared__ unsigned short Vtlds[2][64 * 128];    // 2 x 16 KB, XOR-swizzled
    const int bh = blockIdx.x;
    const int b = bh >> 4, h = bh & 15;
    const int tid = threadIdx.x, wave = tid >> 6, lane = tid & 63;
    const int quad = lane >> 4, l15 = lane & 15;
    const int q0 = blockIdx.y * 128 + wave * 32;

    // Q fragments (mod^2*scale*log2e folded); used as MFMA *B* operand.
    short8 qf[2][2];
#pragma unroll
    for (int g = 0; g < 2; g++) {
        int ss = q0 + g * 16 + l15;
        const unsigned short* crow = Cq + ((size_t)(b * SEQ + ss)) * HIDDEN + h * 64;
#pragma unroll
        for (int kk = 0; kk < 2; kk++) {
            int bd = kk * 32 + quad * 8;
            short8 u = *(const short8*)(crow + bd);
            short8 q;
#pragma unroll
            for (int e = 0; e < 8; e++)
                q[e] = (short)f2bf(bf2f((unsigned short)u[e]) * mod2[h * 64 + bd + e]);
            qf[g][kk] = q;
        }
    }
    // interference weights for the q side: q index = q0 + g*16 + l15 (lane-scalar per g)
    float ci_[2], si_[2];
#pragma unroll
    for (int g = 0; g < 2; g++) {
        ci_[g] = posc[q0 + g * 16 + l15];
        si_[g] = poss[q0 + g * 16 + l15];
    }

    short8 ones;
#pragma unroll
    for (int e = 0; e < 8; e++) ones[e] = (short)0x3F80;

    const f32x4 z4 = {0.f, 0.f, 0.f, 0.f};
    f32x4 acc[2][4], accden[2];
#pragma unroll
    for (int g = 0; g < 2; g++) {
#pragma unroll
        for (int dt = 0; dt < 4; dt++) acc[g][dt] = z4;
        accden[g] = z4;
    }

    const unsigned short* Kbh = Ck  + ((size_t)b * SEQ) * HIDDEN + h * 64;   // row stride HIDDEN
    const unsigned short* Vbh = Vpt + (size_t)bh * 64 * SEQ;                 // row stride SEQ

    auto stage = [&](int j, int buf) {
#pragma unroll
        for (int p = 0; p < 4; p++) {               // K: 128 rows, 8 rows/instr/wave
            int rb = p * 32 + wave * 8;
            int r  = rb + (lane >> 3);
            int c  = (lane & 7) ^ (r & 7);
            gl_lds16(Kbh + (size_t)(j + r) * HIDDEN + c * 8, &Klds[buf][rb * 64]);
        }
#pragma unroll
        for (int p = 0; p < 4; p++) {               // V^T: 64 rows x 128 keys, 4 rows/instr/wave
            int rb = p * 16 + wave * 4;
            int r  = rb + (lane >> 4);
            int c  = (lane & 15) ^ (r & 15);
            gl_lds16(Vbh + (size_t)r * SEQ + j + c * 8, &Vtlds[buf][rb * 128]);
        }
    };

    stage(0, 0);
    const int NIT = SEQ / KT;   // 16
    for (int it = 0; it < NIT; it++) {
        __syncthreads();                 // drains stage(it); prev-buf reads done
        if (it + 1 < NIT) stage((it + 1) * KT, (it + 1) & 1);   // overlap w/ compute
        const int buf = it & 1;

        short8 kfB[2][2];
        f32x4 scA[2][2], scB[2][2];   // scA = scores being softmaxed; scB = lookahead

        // ---- prologue: chunk 0 K-reads + QK
        {
#pragma unroll
            for (int t2i = 0; t2i < 2; t2i++)
#pragma unroll
                for (int kk = 0; kk < 2; kk++) {
                    int ch = (kk * 4 + quad) ^ (l15 & 7);
                    kfB[t2i][kk] = *(const short8*)(&Klds[buf][(t2i * 16 + l15) * 64 + ch * 8]);
                }
            scA[0][0] = z4; scA[0][1] = z4; scA[1][0] = z4; scA[1][1] = z4;
            __builtin_amdgcn_s_setprio(1);
#pragma unroll
            for (int t2i = 0; t2i < 2; t2i++)
#pragma unroll
                for (int kk = 0; kk < 2; kk++) {
                    scA[0][t2i] = mfma16(kfB[t2i][kk], qf[0][kk], scA[0][t2i]);
                    scA[1][t2i] = mfma16(kfB[t2i][kk], qf[1][kk], scA[1][t2i]);
                }
            __builtin_amdgcn_s_setprio(0);
        }

        // ---- 4 chunks of 32 keys, 1-deep QK lookahead
#pragma unroll
        for (int chunk = 0; chunk < 4; chunk++) {
            // V reads for this chunk (independent; latency hides under QK+softmax)
            short8 vb[4];
#pragma unroll
            for (int dt = 0; dt < 4; dt++) {
                int ch = (chunk * 4 + quad) ^ l15;
                vb[dt] = *(const short8*)(&Vtlds[buf][(dt * 16 + l15) * 128 + ch * 8]);
            }
            // next chunk's K reads + QK MFMAs (fills softmax bubbles)
            if (chunk < 3) {
#pragma unroll
                for (int t2i = 0; t2i < 2; t2i++)
#pragma unroll
                    for (int kk = 0; kk < 2; kk++) {
                        int ch = (kk * 4 + quad) ^ (l15 & 7);
                        kfB[t2i][kk] = *(const short8*)(
                            &Klds[buf][((chunk + 1) * 32 + t2i * 16 + l15) * 64 + ch * 8]);
                    }
                scB[0][0] = z4; scB[0][1] = z4; scB[1][0] = z4; scB[1][1] = z4;
                __builtin_amdgcn_s_setprio(1);
#pragma unroll
                for (int t2i = 0; t2i < 2; t2i++)
#pragma unroll
                    for (int kk = 0; kk < 2; kk++) {
                        scB[0][t2i] = mfma16(kfB[t2i][kk], qf[0][kk], scB[0][t2i]);
                        scB[1][t2i] = mfma16(kfB[t2i][kk], qf[1][kk], scB[1][t2i]);
                    }
                __builtin_amdgcn_s_setprio(0);
            }

            // cos/sin for this chunk's 32 keys
            const int jb = it * KT + chunk * 32 + quad * 4;
            f32x4 cjA[2], sjA[2];
            cjA[0] = *(const f32x4*)(posc + jb);
            sjA[0] = *(const f32x4*)(poss + jb);
            cjA[1] = *(const f32x4*)(posc + jb + 16);
            sjA[1] = *(const f32x4*)(poss + jb + 16);

            // softmax + pack + quad-butterfly -> PV A-fragment (consumes scA)
            short8 pa[2];
#pragma unroll
            for (int g = 0; g < 2; g++) {
                unsigned int w_[4];
#pragma unroll
                for (int t2i = 0; t2i < 2; t2i++) {
#pragma unroll
                    for (int hp = 0; hp < 2; hp++) {
                        float wl = ci_[g] * cjA[t2i][2 * hp]     + si_[g] * sjA[t2i][2 * hp];
                        float wh = ci_[g] * cjA[t2i][2 * hp + 1] + si_[g] * sjA[t2i][2 * hp + 1];
                        float pl = __builtin_amdgcn_exp2f(scA[g][t2i][2 * hp]     * wl);
                        float ph = __builtin_amdgcn_exp2f(scA[g][t2i][2 * hp + 1] * wh);
                        unsigned int w;
                        asm("v_cvt_pk_bf16_f32 %0, %1, %2" : "=v"(w) : "v"(pl), "v"(ph));
                        w_[t2i * 2 + hp] = w;
                    }
                }
                auto t02 = __builtin_amdgcn_permlane32_swap(w_[0], w_[2], false, false);
                auto a02 = __builtin_amdgcn_permlane16_swap(t02[0], t02[1], false, false);
                auto t13 = __builtin_amdgcn_permlane32_swap(w_[1], w_[3], false, false);
                auto a13 = __builtin_amdgcn_permlane16_swap(t13[0], t13[1], false, false);
                uint4v pword;
                pword[0] = a02[0]; pword[1] = a13[0]; pword[2] = a02[1]; pword[3] = a13[1];
                pa[g] = __builtin_bit_cast(short8, pword);   // A[row=q l15][k=quad*8+e]
                accden[g] = mfma16(pa[g], ones, accden[g]);
            }

            __builtin_amdgcn_s_setprio(1);
#pragma unroll
            for (int dt = 0; dt < 4; dt++) {
                acc[0][dt] = mfma16(pa[0], vb[dt], acc[0][dt]);
                acc[1][dt] = mfma16(pa[1], vb[dt], acc[1][dt]);
            }
            __builtin_amdgcn_s_setprio(0);

            // rotate lookahead scores
            if (chunk < 3) {
#pragma unroll
                for (int t2i = 0; t2i < 2; t2i++) {
                    scA[0][t2i] = scB[0][t2i];
                    scA[1][t2i] = scB[1][t2i];
                }
            }
        }
    }

#pragma unroll
    for (int g = 0; g < 2; g++) {
        float rinv[4];
#pragma unroll
        for (int r = 0; r < 4; r++) rinv[r] = 1.0f / accden[g][r];
#pragma unroll
        for (int dt = 0; dt < 4; dt++) {
#pragma unroll
            for (int r = 0; r < 4; r++) {
                int q = q0 + g * 16 + quad * 4 + r;
                int d = dt * 16 + l15;
                Ob[((size_t)(b * SEQ + q)) * HIDDEN + h * 64 + d] = f2bf(acc[g][dt][r] * rinv[r]);
            }
        }
    }
}

// ---------------------------------------------------------------- launch
extern "C" void kernel_launch(void* const* d_in, const int* in_sizes, int n_in,
                              void* d_out, int out_size, void* d_ws, size_t ws_size,
                              hipStream_t stream) {
    const float* x  = (const float*)d_in[0];
    const float* Wq = (const float*)d_in[1];
    const float* Wk = (const float*)d_in[2];
    const float* Wv = (const float*)d_in[3];
    const float* Wo = (const float*)d_in[4];
    const float* qp = (const float*)d_in[5];
    const float* qa = (const float*)d_in[6];
    char* ws = (char*)d_ws;

    unsigned short* Xb  = (unsigned short*)(ws);                      // 8 MB (reused as Ob)
    unsigned short* Wt  = (unsigned short*)(ws + (size_t)( 8 << 20)); // 8 MB (4 x 2MB)
    unsigned short* Cq  = (unsigned short*)(ws + (size_t)(16 << 20)); // 8 MB
    unsigned short* Ck  = (unsigned short*)(ws + (size_t)(24 << 20)); // 8 MB
    unsigned short* Cv  = (unsigned short*)(ws + (size_t)(32 << 20)); // 8 MB (holds V*mod)
    unsigned short* Vpt = (unsigned short*)(ws + (size_t)(40 << 20)); // 8 MB
    float* mod  = (float*)(ws + (size_t)(48 << 20));
    float* mod2 = mod + 1024;
    float* posc = mod2 + 1024;
    float* poss = posc + 2048;
    float* out  = (float*)d_out;

    prep_kernel<<<5120, 256, 0, stream>>>(x, Xb, Wq, Wk, Wv, Wo, Wt,
                                          qp, qa, mod, mod2, posc, poss);
    gemm_kernel<<<dim3(32, 16, 3), 256, 0, stream>>>(Xb, Wt, Cq, mod);  // -> Cq,Ck,Cv(modded)
    vshift_kernel<<<dim3(32, 32), 256, 0, stream>>>(Cv, Vpt);
    attn_kernel<<<dim3(32, 16), 256, 0, stream>>>(Cq, Ck, Vpt, Xb /*Ob*/, mod2, posc, poss);
    gemm_o_kernel<<<dim3(32, 16), 256, 0, stream>>>(Xb, Wt + (size_t)3 * HIDDEN * HIDDEN, out);
}